// Round 7
// baseline (177.821 us; speedup 1.0000x reference)
//
#include <hip/hip_runtime.h>
#include <stdint.h>

// SelfBallPointQuery: B=16, C=3, N=2048, RADIUS^2=0.04, MAX_SAMPLES=64.
// R24: de-asm'd test phase. Evidence: R17/R20/R23 (three different feed
// structures, all with hand-forced VOP3P inline asm) converge at K~19-23us
// with VALUBusy 83-85%, ~2x the hand-counted instruction stream. Packed
// f32 on gfx950 is NOT double-rate (FP32 peak 157TF => v_pk_*_f32 = 4cyc
// /wave-inst, same FLOP rate as scalar 2x2cyc), so the asm buys nothing on
// the datapath -- but its "v" constraints on ext_vector(2) operands force
// aligned-pair register placement (VGPR_Count=28!) and block scheduling,
// plausibly inserting the unexplained ~2x v_mov/shuffle overhead.
// This round: identical R23 skeleton (per-wave LDS point strip, compile-
// time offsets, verified epilogue) with plain scalar math:
//   #pragma clang fp contract(off)  -- hipcc defaults contract=fast; an
//   fma changes rounding at the d2<R2 boundary (~0.3 expected flips over
//   67M pairs) so it must be off. Sequence (dx*dx+dy*dy)+dz*dz, each op
//   individually rounded, d=p-q (squares identically to q-p) == reference.
// Compiler is free to: merge constant-offset LDS reads into ds_read_b128,
// schedule across points, lower m=m+m+(d2<R2) to v_cmp+v_addc carry form.
// Epilogue (count/qf/prefix/emit/pad/copy-out) byte-identical to R23.
// Prediction: K 19.4 -> 13-15us (dur ~66-69 at fill~41); if K unchanged,
// asm-overhead theory falsified -> near-roofline arithmetic next round.

#define B_DIM 16
#define N_PTS 2048
#define K_OUT 64
#define R2 0.04f
#define WAVES 16
#define BLOCK_T (WAVES * 64)            // 1024
#define JPW (N_PTS / WAVES)             // 128 points per wave
#define WPW (JPW / 32)                  // 4 mask words per lane
#define ROWPAD 65                       // LDS row stride

typedef float v2f __attribute__((ext_vector_type(2)));

__global__ __launch_bounds__(BLOCK_T, 8) void ball_query_kernel(
    const float* __restrict__ pcs,   // (B, 3, N)
    int* __restrict__ out)           // (B, N, 64) int32
{
#pragma clang fp contract(off)
    __shared__ float shp[WAVES][3][JPW];     // per-wave point strips
    __shared__ int rows[64 * ROWPAD];
    __shared__ int cntS[WAVES][64];
    __shared__ int qfS[WAVES][64];

    const int b    = blockIdx.x >> 5;
    const int qg   = blockIdx.x & 31;
    const int tid  = threadIdx.x;
    const int wave = __builtin_amdgcn_readfirstlane(tid >> 6); // uniform
    const int lane = tid & 63;

    const float* __restrict__ sx = pcs + (size_t)b * 3 * N_PTS;
    const float* __restrict__ sy = sx + N_PTS;
    const float* __restrict__ sz = sy + N_PTS;

    const int jbase = wave * JPW;
    const int qb    = qg * 64;
    int* const obase = out + (size_t)(b * N_PTS + qb) * K_OUT;

    // ---- stage this wave's 128 points into its LDS strip (coalesced) ----
    *(v2f*)&shp[wave][0][2 * lane] = *(const v2f*)(sx + jbase + 2 * lane);
    *(v2f*)&shp[wave][1][2 * lane] = *(const v2f*)(sy + jbase + 2 * lane);
    *(v2f*)&shp[wave][2][2 * lane] = *(const v2f*)(sz + jbase + 2 * lane);

    // ---- per-lane query, pre-negated ----
    const int qi = qb + lane;
    const float nx = -sx[qi], ny = -sy[qi], nz = -sz[qi];

    __syncthreads();   // staging visible (also orders cross-lane LDS reads)

    const float* __restrict__ wx = &shp[wave][0][0];
    const float* __restrict__ wy = &shp[wave][1][0];
    const float* __restrict__ wz = &shp[wave][2][0];

    // ---- dense test phase: 4 words x 32 bits, descending bit deposit ----
    unsigned mask[WPW];
    #pragma unroll
    for (int t = 0; t < WPW; ++t) {
        unsigned m = 0;
        #pragma unroll
        for (int k = 31; k >= 0; --k) {       // bit k <- point t*32 + k
            const int j = t * 32 + k;         // compile-time offset
            const float dx = wx[j] + nx;      // p - q (exact negation)
            const float dy = wy[j] + ny;
            const float dz = wz[j] + nz;
            const float xx = dx * dx;
            const float yy = dy * dy;
            const float zz = dz * dz;
            const float d2 = (xx + yy) + zz;  // reference sum order
            m = m + m + (unsigned)(d2 < R2);
        }
        mask[t] = m;
    }

    // per-lane count + first hit within this wave's window
    int cnt = 0;
    #pragma unroll
    for (int t = 0; t < WPW; ++t) cnt += __builtin_popcount(mask[t]);
    int qf = -1;
    #pragma unroll
    for (int t = 0; t < WPW; ++t) {
        if (qf < 0 && mask[t] != 0u)
            qf = jbase + t * 32 + __builtin_ctz(mask[t]);
    }
    cntS[wave][lane] = cnt;
    qfS[wave][lane]  = qf;
    __syncthreads();

    // prefix over earlier waves' counts for my query; global first hit
    int base = 0, tc = 0, gfirst = 0;
    #pragma unroll
    for (int w = 0; w < WAVES; ++w) {
        const int c = cntS[w][lane];
        const int f = qfS[w][lane];
        if (w < wave) base += c;
        gfirst = (tc == 0 && c > 0) ? f : gfirst;
        tc += c;
    }

    // ---- sparse emit into LDS rows (disjoint slot ranges across waves) ----
    int slot = base;
    for (int t = 0; t < WPW; ++t) {
        unsigned m = mask[t];
        while (m != 0u && slot < K_OUT) {
            const int k = (int)__builtin_ctz(m);
            rows[lane * ROWPAD + slot] = jbase + t * 32 + k;
            m &= m - 1u;
            ++slot;
        }
    }

    // ---- pad: 4 slots per wave cover [0,64); fill gfirst where s >= tc ----
    #pragma unroll
    for (int s0i = 0; s0i < K_OUT / WAVES; ++s0i) {
        const int s = wave * (K_OUT / WAVES) + s0i;
        if (s >= tc) rows[lane * ROWPAD + s] = gfirst;
    }
    __syncthreads();

    // ---- coalesced copy-out: 64 rows x 64 ints ----
    #pragma unroll
    for (int it = 0; it < (64 * K_OUT) / BLOCK_T; ++it) {
        const int idx = it * BLOCK_T + tid;
        const int r = idx >> 6;
        const int c = idx & 63;
        obase[idx] = rows[r * ROWPAD + c];
    }
}

extern "C" void kernel_launch(void* const* d_in, const int* in_sizes, int n_in,
                              void* d_out, int out_size, void* d_ws, size_t ws_size,
                              hipStream_t stream) {
    const float* pcs = (const float*)d_in[0];
    int* out = (int*)d_out;
    const int grid = B_DIM * 32;     // 512 blocks
    ball_query_kernel<<<grid, BLOCK_T, 0, stream>>>(pcs, out);
}

// Round 8
// 76.251 us; speedup vs baseline: 2.3321x; 2.3321x over previous
//
#include <hip/hip_runtime.h>
#include <stdint.h>

// SelfBallPointQuery: B=16, C=3, N=2048, RADIUS^2=0.04, MAX_SAMPLES=64.
// R25 = R24 (scalar math, LDS point strips, addc bitpack) with the unroll
// BOUNDED to stop the spill catastrophe R24's counters exposed:
//   R24: FETCH 149MB / WRITE 296MB per dispatch (I/O is 0.38/8.4MB),
//   VALUBusy 16%, kernel 120-149us -> full 128-iter unroll let the
//   scheduler hoist all LDS loads, live ranges blew past the VGPR budget,
//   scratch spill through HBM. The R23 inline asm had been acting as an
//   accidental scheduling fence; scalar needs an explicit unroll bound.
// Inner loop: #pragma unroll 8 -> ~24 live LDS floats + ~10 temps, no
// spill, still enough ILP to cover the serial m=m+m+carry addc chain.
// Scalar per point: 8 individually-rounded flops + v_cmp + v_addc =
// 10 inst = 20 cyc/pt -- provably the same datapath cost as the packed
// VOP3P variant (pk f32 is 4cyc/wave, not double-rate) minus the operand
// alignment/deposit plumbing that R20/R23 paid (K ~19-23us, VALUBusy 84%).
// fp contract(off): hipcc defaults to contract=fast; an fma would change
// rounding at the d2<R2 boundary (~0.4 expected flips over 67M pairs).
// Sum order (dx*dx+dy*dy)+dz*dz, d=p-q == reference bit-exact.
// Epilogue (count/qf/prefix/emit/pad/copy-out) byte-identical to R20-R24.
// Prediction: FETCH ~1.7MB, WRITE ~8MB, K 19.4 -> 13-16us, dur ~66-70
// (fill-median-relative). If K returns to ~19-22, four structures bracket
// the floor -> revert to best (R20) and close.

#define B_DIM 16
#define N_PTS 2048
#define K_OUT 64
#define R2 0.04f
#define WAVES 16
#define BLOCK_T (WAVES * 64)            // 1024
#define JPW (N_PTS / WAVES)             // 128 points per wave
#define WPW (JPW / 32)                  // 4 mask words per lane
#define ROWPAD 65                       // LDS row stride

typedef float v2f __attribute__((ext_vector_type(2)));

__global__ __launch_bounds__(BLOCK_T, 8) void ball_query_kernel(
    const float* __restrict__ pcs,   // (B, 3, N)
    int* __restrict__ out)           // (B, N, 64) int32
{
#pragma clang fp contract(off)
    __shared__ float shp[WAVES][3][JPW];     // per-wave point strips
    __shared__ int rows[64 * ROWPAD];
    __shared__ int cntS[WAVES][64];
    __shared__ int qfS[WAVES][64];

    const int b    = blockIdx.x >> 5;
    const int qg   = blockIdx.x & 31;
    const int tid  = threadIdx.x;
    const int wave = __builtin_amdgcn_readfirstlane(tid >> 6); // uniform
    const int lane = tid & 63;

    const float* __restrict__ sx = pcs + (size_t)b * 3 * N_PTS;
    const float* __restrict__ sy = sx + N_PTS;
    const float* __restrict__ sz = sy + N_PTS;

    const int jbase = wave * JPW;
    const int qb    = qg * 64;
    int* const obase = out + (size_t)(b * N_PTS + qb) * K_OUT;

    // ---- stage this wave's 128 points into its LDS strip (coalesced) ----
    *(v2f*)&shp[wave][0][2 * lane] = *(const v2f*)(sx + jbase + 2 * lane);
    *(v2f*)&shp[wave][1][2 * lane] = *(const v2f*)(sy + jbase + 2 * lane);
    *(v2f*)&shp[wave][2][2 * lane] = *(const v2f*)(sz + jbase + 2 * lane);

    // ---- per-lane query, pre-negated ----
    const int qi = qb + lane;
    const float nx = -sx[qi], ny = -sy[qi], nz = -sz[qi];

    __syncthreads();   // staging visible (also orders cross-lane LDS reads)

    const float* __restrict__ wx = &shp[wave][0][0];
    const float* __restrict__ wy = &shp[wave][1][0];
    const float* __restrict__ wz = &shp[wave][2][0];

    // ---- dense test phase: 4 words x 32 bits, descending bit deposit ----
    unsigned mask[WPW];
    for (int t = 0; t < WPW; ++t) {           // 4 iterations, not unrolled
        unsigned m = 0;
        #pragma unroll 8
        for (int k = 31; k >= 0; --k) {       // bit k <- point t*32 + k
            const int j = t * 32 + k;
            const float dx = wx[j] + nx;      // p - q (exact negation)
            const float dy = wy[j] + ny;
            const float dz = wz[j] + nz;
            const float xx = dx * dx;
            const float yy = dy * dy;
            const float zz = dz * dz;
            const float d2 = (xx + yy) + zz;  // reference sum order
            m = m + m + (unsigned)(d2 < R2);
        }
        mask[t] = m;
    }

    // per-lane count + first hit within this wave's window
    int cnt = 0;
    #pragma unroll
    for (int t = 0; t < WPW; ++t) cnt += __builtin_popcount(mask[t]);
    int qf = -1;
    #pragma unroll
    for (int t = 0; t < WPW; ++t) {
        if (qf < 0 && mask[t] != 0u)
            qf = jbase + t * 32 + __builtin_ctz(mask[t]);
    }
    cntS[wave][lane] = cnt;
    qfS[wave][lane]  = qf;
    __syncthreads();

    // prefix over earlier waves' counts for my query; global first hit
    int base = 0, tc = 0, gfirst = 0;
    #pragma unroll
    for (int w = 0; w < WAVES; ++w) {
        const int c = cntS[w][lane];
        const int f = qfS[w][lane];
        if (w < wave) base += c;
        gfirst = (tc == 0 && c > 0) ? f : gfirst;
        tc += c;
    }

    // ---- sparse emit into LDS rows (disjoint slot ranges across waves) ----
    int slot = base;
    for (int t = 0; t < WPW; ++t) {
        unsigned m = mask[t];
        while (m != 0u && slot < K_OUT) {
            const int k = (int)__builtin_ctz(m);
            rows[lane * ROWPAD + slot] = jbase + t * 32 + k;
            m &= m - 1u;
            ++slot;
        }
    }

    // ---- pad: 4 slots per wave cover [0,64); fill gfirst where s >= tc ----
    #pragma unroll
    for (int s0i = 0; s0i < K_OUT / WAVES; ++s0i) {
        const int s = wave * (K_OUT / WAVES) + s0i;
        if (s >= tc) rows[lane * ROWPAD + s] = gfirst;
    }
    __syncthreads();

    // ---- coalesced copy-out: 64 rows x 64 ints ----
    #pragma unroll
    for (int it = 0; it < (64 * K_OUT) / BLOCK_T; ++it) {
        const int idx = it * BLOCK_T + tid;
        const int r = idx >> 6;
        const int c = idx & 63;
        obase[idx] = rows[r * ROWPAD + c];
    }
}

extern "C" void kernel_launch(void* const* d_in, const int* in_sizes, int n_in,
                              void* d_out, int out_size, void* d_ws, size_t ws_size,
                              hipStream_t stream) {
    const float* pcs = (const float*)d_in[0];
    int* out = (int*)d_out;
    const int grid = B_DIM * 32;     // 512 blocks
    ball_query_kernel<<<grid, BLOCK_T, 0, stream>>>(pcs, out);
}

// Round 9
// 73.695 us; speedup vs baseline: 2.4129x; 1.0347x over previous
//
#include <hip/hip_runtime.h>
#include <stdint.h>

// SelfBallPointQuery: B=16, C=3, N=2048, RADIUS^2=0.04, MAX_SAMPLES=64.
// R26 = REVERT TO BEST (R20, dur 73.8us, absmax 0.0). Closure candidate.
// Session evidence bracket (R21 slope + R22 PMC + 4 structural variants):
//   - fixed harness term ~53us (41us poison fill + ~12us launch/small ops)
//   - kernel K: R20=21, R17=23, R23=22.8, R25=23.5us -- four independent
//     test-phase structures (SMEM-fed packed, ballot-deposit packed,
//     LDS-fed packed, LDS-fed scalar) converge at K ~= 20-23us
//   - R22 PMC at 4x grid: VALUBusy 83-85%, HBM 1.6%, LDS conflicts ~1%,
//     occupancy 77% -> VALU-issue bound
//   - datapath floor (8 individually-rounded flops + cmp + pack, no FMA
//     by bit-exactness, pk-f32 not double-rate) ~= 10us; consistent ~2x
//     residual across ALL variants, not localizable without disasm, and
//     bounded recovery (<8us) on a 53us-fixed-dominated metric.
// Structure: inverted broadcast. Points in VGPRs (2/lane, packed v2f);
// queries via 24x wide uniform loads; per step 8 VOP3P pk -> d2 pair,
// 2 ballots -> wave-uniform masks (bit i == point jbase+set*64+i),
// lane==q guarded deposit. Epilogue: count/qf -> cross-wave prefix ->
// sparse emit into disjoint LDS slot ranges -> gfirst pad -> coalesced
// copy-out. FP: d=(-q)+p (sign-flip exact), squares rounded individually,
// (x^2+y^2)+z^2 == reference order, bit-exact.

#define B_DIM 16
#define N_PTS 2048
#define K_OUT 64
#define R2 0.04f
#define WAVES 16
#define BLOCK_T (WAVES * 64)            // 1024
#define JPW (N_PTS / WAVES)             // 128 points per wave
#define WPW (JPW / 32)                  // 4 mask words per lane
#define ROWPAD 65                       // LDS row stride

typedef float v2f __attribute__((ext_vector_type(2)));
typedef float f32x8 __attribute__((ext_vector_type(8)));

__global__ __launch_bounds__(BLOCK_T, 8) void ball_query_kernel(
    const float* __restrict__ pcs,   // (B, 3, N)
    int* __restrict__ out)           // (B, N, 64) int32
{
    __shared__ int rows[64 * ROWPAD];
    __shared__ int cntS[WAVES][64];
    __shared__ int qfS[WAVES][64];

    const int b    = blockIdx.x >> 5;
    const int qg   = blockIdx.x & 31;
    const int tid  = threadIdx.x;
    const int wave = __builtin_amdgcn_readfirstlane(tid >> 6); // uniform
    const int lane = tid & 63;

    const float* __restrict__ sx = pcs + (size_t)b * 3 * N_PTS;
    const float* __restrict__ sy = sx + N_PTS;
    const float* __restrict__ sz = sy + N_PTS;

    const int jbase = wave * JPW;
    const int qb    = qg * 64;
    int* const obase = out + (size_t)(b * N_PTS + qb) * K_OUT;

    // ---- wave-resident points: set0 = jbase+lane, set1 = jbase+64+lane ----
    v2f px, py, pz;
    px.x = sx[jbase + lane]; px.y = sx[jbase + 64 + lane];
    py.x = sy[jbase + lane]; py.y = sy[jbase + 64 + lane];
    pz.x = sz[jbase + lane]; pz.y = sz[jbase + 64 + lane];

    // per-lane mask words (lane = query), filled by guarded deposit
    unsigned w0 = 0, w1 = 0, w2 = 0, w3 = 0;

    #pragma unroll
    for (int c = 0; c < 8; ++c) {
        // 8 queries' coords per chunk, uniform address -> wide scalar loads
        const f32x8 qxv = *(const f32x8*)(sx + qb + c * 8);
        const f32x8 qyv = *(const f32x8*)(sy + qb + c * 8);
        const f32x8 qzv = *(const f32x8*)(sz + qb + c * 8);
        #pragma unroll
        for (int s = 0; s < 8; ++s) {
            const int q = c * 8 + s;
            // negate via sign-bit flip (exact)
            const unsigned bx = __float_as_uint(qxv[s]) ^ 0x80000000u;
            const unsigned by = __float_as_uint(qyv[s]) ^ 0x80000000u;
            const unsigned bz = __float_as_uint(qzv[s]) ^ 0x80000000u;
            v2f nX, nY, nZ;
            nX.x = nX.y = __uint_as_float(bx);
            nY.x = nY.y = __uint_as_float(by);
            nZ.x = nZ.y = __uint_as_float(bz);
            v2f dx, dy, dz, xx, yy, zz, s0, d2;
            asm("v_pk_add_f32 %0, %1, %2" : "=v"(dx) : "s"(nX), "v"(px));
            asm("v_pk_add_f32 %0, %1, %2" : "=v"(dy) : "s"(nY), "v"(py));
            asm("v_pk_add_f32 %0, %1, %2" : "=v"(dz) : "s"(nZ), "v"(pz));
            asm("v_pk_mul_f32 %0, %1, %1" : "=v"(xx) : "v"(dx));
            asm("v_pk_mul_f32 %0, %1, %1" : "=v"(yy) : "v"(dy));
            asm("v_pk_mul_f32 %0, %1, %1" : "=v"(zz) : "v"(dz));
            asm("v_pk_add_f32 %0, %1, %2" : "=v"(s0) : "v"(xx), "v"(yy));
            asm("v_pk_add_f32 %0, %1, %2" : "=v"(d2) : "v"(s0), "v"(zz));
            // wave-uniform hit masks: bit i == point jbase + (set*64) + i
            const unsigned long long b0 = __ballot(d2.x < R2);
            const unsigned long long b1 = __ballot(d2.y < R2);
            // deposit query q's 4 mask words into lane q (uniform sources)
            if (lane == q) {
                w0 = (unsigned)b0;
                w1 = (unsigned)(b0 >> 32);
                w2 = (unsigned)b1;
                w3 = (unsigned)(b1 >> 32);
            }
        }
    }

    unsigned mask[WPW] = { w0, w1, w2, w3 };

    // per-lane count + first hit within this wave's window
    int cnt = 0;
    #pragma unroll
    for (int t = 0; t < WPW; ++t) cnt += __builtin_popcount(mask[t]);
    int qf = -1;
    #pragma unroll
    for (int t = 0; t < WPW; ++t) {
        if (qf < 0 && mask[t] != 0u)
            qf = jbase + t * 32 + __builtin_ctz(mask[t]);
    }
    cntS[wave][lane] = cnt;
    qfS[wave][lane]  = qf;
    __syncthreads();

    // prefix over earlier waves' counts for my query; global first hit
    int base = 0, tc = 0, gfirst = 0;
    #pragma unroll
    for (int w = 0; w < WAVES; ++w) {
        const int c = cntS[w][lane];
        const int f = qfS[w][lane];
        if (w < wave) base += c;
        gfirst = (tc == 0 && c > 0) ? f : gfirst;
        tc += c;
    }

    // ---- sparse emit into LDS rows (disjoint slot ranges across waves) ----
    int slot = base;
    for (int t = 0; t < WPW; ++t) {
        unsigned m = mask[t];
        while (m != 0u && slot < K_OUT) {
            const int k = (int)__builtin_ctz(m);
            rows[lane * ROWPAD + slot] = jbase + t * 32 + k;
            m &= m - 1u;
            ++slot;
        }
    }

    // ---- pad: 4 slots per wave cover [0,64); fill gfirst where s >= tc ----
    #pragma unroll
    for (int s0i = 0; s0i < K_OUT / WAVES; ++s0i) {
        const int s = wave * (K_OUT / WAVES) + s0i;
        if (s >= tc) rows[lane * ROWPAD + s] = gfirst;
    }
    __syncthreads();

    // ---- coalesced copy-out: 64 rows x 64 ints ----
    #pragma unroll
    for (int it = 0; it < (64 * K_OUT) / BLOCK_T; ++it) {
        const int idx = it * BLOCK_T + tid;
        const int r = idx >> 6;
        const int c = idx & 63;
        obase[idx] = rows[r * ROWPAD + c];
    }
}

extern "C" void kernel_launch(void* const* d_in, const int* in_sizes, int n_in,
                              void* d_out, int out_size, void* d_ws, size_t ws_size,
                              hipStream_t stream) {
    const float* pcs = (const float*)d_in[0];
    int* out = (int*)d_out;
    const int grid = B_DIM * 32;     // 512 blocks
    ball_query_kernel<<<grid, BLOCK_T, 0, stream>>>(pcs, out);
}